// Round 1
// baseline (3828.719 us; speedup 1.0000x reference)
//
#include <hip/hip_runtime.h>
#include <hip/hip_cooperative_groups.h>
#include <cstdint>

namespace cg = cooperative_groups;

#define NN0 80000
#define NE 1280000
#define MMB_GRID 2048
#define EB 2048          // elems per block in edge sort (NE/EB = 625 exact)
#define ENB 625

static inline int cdiv(int a, int b){ return (a+b-1)/b; }

// ======================= plain (non-cooperative) conv kernels =======================

// ---- FUSED conv: gather (x-space) + matmul [64,64] + BN partials ----
__global__ void k_conv64(const int* __restrict__ rp, const int* __restrict__ col,
                         const float* __restrict__ dinv, const float* __restrict__ x,
                         const float* __restrict__ W, float* __restrict__ out,
                         float* __restrict__ part, int n){
  __shared__ float yl[4][64];
  __shared__ float ls[64], lq[64];
  int lane = threadIdx.x & 63, w = threadIdx.x >> 6;
  if (threadIdx.x < 64){ ls[threadIdx.x] = 0.f; lq[threadIdx.x] = 0.f; }
  __syncthreads();
  float sa = 0.f, sq = 0.f;
  int wid = blockIdx.x*4 + w, nw = gridDim.x*4;
  for (int i = wid; i < n; i += nw){
    int beg = rp[i], end = rp[i+1];
    float di = dinv[i];
    float y = 0.f;
    int j = beg;
    for (; j + 4 <= end; j += 4){
      int s0 = col[j], s1 = col[j+1], s2 = col[j+2], s3 = col[j+3];
      float y0 = dinv[s0]*x[s0*64+lane];
      float y1 = dinv[s1]*x[s1*64+lane];
      float y2 = dinv[s2]*x[s2*64+lane];
      float y3 = dinv[s3]*x[s3*64+lane];
      y += (y0+y1) + (y2+y3);
    }
    for (; j < end; j++){ int s = col[j]; y += dinv[s]*x[s*64+lane]; }
    y = di*y + 2.f*di*di*x[i*64+lane];
    yl[w][lane] = y;
    float acc = 0.f;
    #pragma unroll
    for (int k2 = 0; k2 < 64; k2++)
      acc += yl[w][k2]*W[k2*64+lane];
    out[i*64+lane] = acc;
    sa += acc; sq += acc*acc;
  }
  atomicAdd(&ls[lane], sa); atomicAdd(&lq[lane], sq);
  __syncthreads();
  if (threadIdx.x < 128)
    part[blockIdx.x*128 + threadIdx.x] =
      (threadIdx.x < 64) ? ls[threadIdx.x] : lq[threadIdx.x-64];
}

// FUSED first conv (Fin=3)
__global__ void k_conv3(const int* __restrict__ rp, const int* __restrict__ col,
                        const float* __restrict__ dinv, const float* __restrict__ x,
                        const float* __restrict__ W, float* __restrict__ out,
                        float* __restrict__ part, int n){
  __shared__ float ls[64], lq[64];
  int lane = threadIdx.x & 63, w = threadIdx.x >> 6;
  if (threadIdx.x < 64){ ls[threadIdx.x] = 0.f; lq[threadIdx.x] = 0.f; }
  __syncthreads();
  float wf0 = W[lane], wf1 = W[64+lane], wf2 = W[128+lane];
  float sa = 0.f, sq = 0.f;
  int wid = blockIdx.x*4 + w, nw = gridDim.x*4;
  for (int i = wid; i < n; i += nw){
    int beg = rp[i], end = rp[i+1];
    float a0 = 0.f, a1 = 0.f, a2 = 0.f;
    for (int j = beg + lane; j < end; j += 64){
      int s2 = col[j];
      float ds = dinv[s2];
      a0 += ds*x[s2*3+0]; a1 += ds*x[s2*3+1]; a2 += ds*x[s2*3+2];
    }
    for (int o = 32; o > 0; o >>= 1){
      a0 += __shfl_xor(a0, o); a1 += __shfl_xor(a1, o); a2 += __shfl_xor(a2, o);
    }
    float di = dinv[i];
    float sl = 2.f*di*di;
    a0 = di*a0 + sl*x[i*3+0];
    a1 = di*a1 + sl*x[i*3+1];
    a2 = di*a2 + sl*x[i*3+2];
    float s = a0*wf0 + a1*wf1 + a2*wf2;
    out[i*64+lane] = s; sa += s; sq += s*s;
  }
  atomicAdd(&ls[lane], sa); atomicAdd(&lq[lane], sq);
  __syncthreads();
  if (threadIdx.x < 128)
    part[blockIdx.x*128 + threadIdx.x] =
      (threadIdx.x < 64) ? ls[threadIdx.x] : lq[threadIdx.x-64];
}

// ======================= device phases for cooperative kernels =======================

// BN partial reduction: 2048x128 part -> 128 stats (deterministic, same order as before)
static __device__ void stats_phase(const float* part, float* stats){
  int lane = threadIdx.x & 63, w = threadIdx.x >> 6;
  for (int c = blockIdx.x*4 + w; c < 128; c += gridDim.x*4){
    float s = 0.f;
    for (int b = lane; b < MMB_GRID; b += 64) s += part[b*128 + c];
    for (int o = 32; o > 0; o >>= 1) s += __shfl_xor(s, o);
    if (lane == 0) stats[c] = s;
  }
}

// ---- edge radix sort phases (6-bit digits) ----
static __device__ void ehist_phase(const int* key, int* hist, int shift){
  __shared__ int lh[64];
  for (int vb = blockIdx.x; vb < ENB; vb += gridDim.x){
    if (threadIdx.x < 64) lh[threadIdx.x] = 0;
    __syncthreads();
    int base = vb*EB + threadIdx.x;
    #pragma unroll
    for (int u = 0; u < 8; u++)
      atomicAdd(&lh[(key[base + u*256] >> shift) & 63], 1);
    __syncthreads();
    if (threadIdx.x < 64) hist[threadIdx.x*ENB + vb] = lh[threadIdx.x];
    __syncthreads();
  }
}

// scatter computes its own dbase from the raw histogram (no separate global scan)
static __device__ void escatter_phase(const int* keyin, const int* valin,
                                      int* keyout, int* valout,
                                      const int* hist, int shift){
  __shared__ int dbase[64], run[64], wcnt[4][64];
  __shared__ int ptot[4][64], ppre[4][64];
  int t = threadIdx.x, lane = t & 63, w = t >> 6;
  for (int vb = blockIdx.x; vb < ENB; vb += gridDim.x){
    // per-digit totals and prefix over blocks < vb, split 4-ways over threads
    {
      int b0 = w*157, b1 = b0 + 157; if (b1 > ENB) b1 = ENB;
      int pre = 0, tot = 0;
      for (int b = b0; b < b1; b++){
        int v = hist[lane*ENB + b];
        if (b < vb) pre += v;
        tot += v;
      }
      ptot[w][lane] = tot; ppre[w][lane] = pre;
    }
    __syncthreads();
    if (t < 64){
      int tt = ptot[0][t]+ptot[1][t]+ptot[2][t]+ptot[3][t];
      int pp = ppre[0][t]+ppre[1][t]+ppre[2][t]+ppre[3][t];
      int xv = tt;
      for (int o = 1; o < 64; o <<= 1){
        int y = __shfl_up(xv, o);
        if (lane >= o) xv += y;
      }
      dbase[t] = (xv - tt) + pp;   // exclusive digit scan + block prefix
      run[t] = 0;
    }
    __syncthreads();
    for (int u = 0; u < 8; u++){
      if (t < 64){ wcnt[0][t]=0; wcnt[1][t]=0; wcnt[2][t]=0; wcnt[3][t]=0; }
      __syncthreads();
      int g = vb*EB + u*256 + t;
      int kk = keyin[g], vv = valin[g];
      int d = (kk >> shift) & 63;
      unsigned long long m = ~0ull;
      #pragma unroll
      for (int b = 0; b < 6; b++){
        unsigned long long bal = __ballot((d >> b) & 1);
        m &= ((d >> b) & 1) ? bal : ~bal;
      }
      int rnk = __popcll(m & ((1ull << lane) - 1ull));
      if (rnk == 0) wcnt[w][d] = __popcll(m);
      __syncthreads();
      int off2 = run[d] + rnk;
      for (int w2 = 0; w2 < w; w2++) off2 += wcnt[w2][d];
      int pos = dbase[d] + off2;
      keyout[pos] = kk; valout[pos] = vv;
      __syncthreads();
      if (t < 64) run[t] += wcnt[0][t] + wcnt[1][t] + wcnt[2][t] + wcnt[3][t];
      __syncthreads();
    }
  }
}

static __device__ void rp_search_phase(const int* skey, int* rp,
                                       float* dA, float* dB, int n){
  for (int i = blockIdx.x*blockDim.x + threadIdx.x; i < n; i += gridDim.x*blockDim.x){
    int lo = 0, hi = NE;
    while (lo < hi){ int mid = (lo+hi)>>1; if (skey[mid] < i) lo = mid+1; else hi = mid; }
    int a2 = lo;
    lo = a2; hi = NE;
    while (lo < hi){ int mid = (lo+hi)>>1; if (skey[mid] < i+1) lo = mid+1; else hi = mid; }
    int b2 = lo;
    rp[i] = a2;
    if (i == n-1) rp[n] = NE;
    float deg = (float)(b2 - a2);
    dA[i] = 1.0f/sqrtf(deg + 2.f);
    dB[i] = 1.0f/sqrtf(deg + 1.f);
  }
}

// ---- generic scans (used for child-CSR build) ----
static __device__ void scan_part_phase(const int* in, int* bsumv, int n2){
  __shared__ int ws[256];
  int nb = (n2 + 2047) >> 11;
  for (int vb = blockIdx.x; vb < nb; vb += gridDim.x){
    int base = vb*2048 + threadIdx.x*8;
    int s = 0;
    #pragma unroll
    for (int u = 0; u < 8; u++){ int i = base+u; if (i < n2) s += in[i]; }
    ws[threadIdx.x] = s; __syncthreads();
    for (int st = 128; st > 0; st >>= 1){
      if (threadIdx.x < st) ws[threadIdx.x] += ws[threadIdx.x+st];
      __syncthreads();
    }
    if (threadIdx.x == 0) bsumv[vb] = ws[0];
    __syncthreads();
  }
}

static __device__ void scan_fin_rp_phase(const int* in, const int* bsumv,
                                         int* rp, float* dinvv, int n){
  __shared__ int bws[256]; __shared__ int ws[256];
  int nb = (n + 2047) >> 11;
  int t = threadIdx.x;
  for (int vb = blockIdx.x; vb < nb; vb += gridDim.x){
    bws[t] = (t < nb) ? bsumv[t] : 0; __syncthreads();
    for (int st = 1; st < 256; st <<= 1){
      int a = (t >= st) ? bws[t-st] : 0; __syncthreads();
      bws[t] += a; __syncthreads();
    }
    int blockoff = (vb == 0) ? 0 : bws[vb-1];
    int base = vb*2048 + t*8;
    int v[8]; int s = 0;
    #pragma unroll
    for (int u = 0; u < 8; u++){ int i = base+u; v[u] = (i < n) ? in[i] : 0; s += v[u]; }
    ws[t] = s; __syncthreads();
    for (int st = 1; st < 256; st <<= 1){
      int a = (t >= st) ? ws[t-st] : 0; __syncthreads();
      ws[t] += a; __syncthreads();
    }
    int off = blockoff + ws[t] - s;
    #pragma unroll
    for (int u = 0; u < 8; u++){
      int i = base+u;
      if (i < n){
        rp[i] = off; off += v[u];
        dinvv[i] = 1.0f/sqrtf((float)v[u] + 2.f);
        if (i == n-1) rp[n] = off;
      }
    }
    __syncthreads();
  }
}

// ---- pool phases ----
static __device__ void bnrelu_score_phase(float* x, const float* stats,
    const float* gamma, const float* beta, const float* pw,
    float* score, unsigned* key, int* idx, int n, int P){
  int lane = threadIdx.x & 63, w = threadIdx.x >> 6;
  int wid = blockIdx.x*4 + w, nw = gridDim.x*4;
  float inv_n = 1.f/(float)n;
  float mu = stats[lane]*inv_n;
  float var = stats[64+lane]*inv_n - mu*mu;
  float gs = gamma[lane]*(1.f/sqrtf(var+1e-5f));
  float bt = beta[lane];
  float pv = pw[lane];
  float q = pv*pv;
  for (int o = 32; o > 0; o >>= 1) q += __shfl_xor(q, o);
  float qn = 1.f/sqrtf(q);
  for (int i = wid; i < n; i += nw){
    float v = fmaxf(gs*(x[i*64+lane]-mu)+bt, 0.f);
    x[i*64+lane] = v;
    float s = v*pv;
    for (int o = 32; o > 0; o >>= 1) s += __shfl_xor(s, o);
    if (lane == 0){
      float sc = fmaxf(s*qn, 0.f);
      score[i] = sc; key[i] = ~__float_as_uint(sc); idx[i] = i;
    }
  }
  for (int g = n + wid; g < P; g += nw)
    if (lane == 0){ key[g] = 0xFFFFFFFFu; idx[g] = 0; }
}

static __device__ void radix_hist_phase(const unsigned* key, int* hist, int shift, int nblk){
  __shared__ int lh[256];
  for (int vb = blockIdx.x; vb < nblk; vb += gridDim.x){
    lh[threadIdx.x] = 0; __syncthreads();
    int base = vb*1024 + threadIdx.x;
    #pragma unroll
    for (int u = 0; u < 4; u++){
      unsigned d = (key[base + u*256] >> shift) & 255u;
      atomicAdd(&lh[d], 1);
    }
    __syncthreads();
    hist[threadIdx.x*nblk + vb] = lh[threadIdx.x];
    __syncthreads();
  }
}

static __device__ void radix_scatter_phase(const unsigned* keyin, const int* idxin,
    unsigned* keyout, int* idxout, const int* hist, int shift, int nblk){
  __shared__ int dbase[256], run[256], sc[256];
  __shared__ int wcnt4[4][256];
  int t = threadIdx.x, lane = t & 63, w = t >> 6;
  for (int vb = blockIdx.x; vb < nblk; vb += gridDim.x){
    int pre = 0, tot = 0;
    for (int b = 0; b < nblk; b++){
      int v = hist[t*nblk + b];
      if (b < vb) pre += v;
      tot += v;
    }
    sc[t] = tot; __syncthreads();
    for (int st = 1; st < 256; st <<= 1){
      int a = (t >= st) ? sc[t-st] : 0; __syncthreads();
      sc[t] += a; __syncthreads();
    }
    dbase[t] = sc[t] - tot + pre;
    run[t] = 0;
    for (int u = 0; u < 4; u++){
      wcnt4[0][t] = 0; wcnt4[1][t] = 0; wcnt4[2][t] = 0; wcnt4[3][t] = 0;
      __syncthreads();
      int g = vb*1024 + u*256 + t;
      unsigned kk = keyin[g]; int id = idxin[g];
      unsigned d = (kk >> shift) & 255u;
      unsigned long long m = ~0ull;
      #pragma unroll
      for (int b = 0; b < 8; b++){
        unsigned long long bal = __ballot((d >> b) & 1u);
        m &= ((d >> b) & 1u) ? bal : ~bal;
      }
      int rnk = __popcll(m & ((1ull << lane) - 1ull));
      if (rnk == 0) wcnt4[w][d] = __popcll(m);
      __syncthreads();
      int off2 = run[d] + rnk;
      for (int w2 = 0; w2 < w; w2++) off2 += wcnt4[w2][d];
      int pos = dbase[d] + off2;
      keyout[pos] = kk; idxout[pos] = id;
      __syncthreads();
      run[t] += wcnt4[0][t] + wcnt4[1][t] + wcnt4[2][t] + wcnt4[3][t];
      __syncthreads();
    }
  }
}

static __device__ void select_gather_phase(const int* idxs, const float* x,
    const float* score, int* perm, int* mapv, float* xk, int n, int k){
  int total = k*64;  // >= n always (k = n/2)
  for (int t = blockIdx.x*blockDim.x + threadIdx.x; t < total; t += gridDim.x*blockDim.x){
    if (t < n){
      int i = idxs[t];
      mapv[i] = (t < k) ? t : -1;
      if (t < k) perm[t] = i;
    }
    int r = t >> 6, f = t & 63;
    int i = idxs[r];
    xk[t] = x[i*64+f]*score[i];
  }
}

static __device__ void hist_mapped_phase(const int* rp_p, const int* col_p,
                                         const int* mapv, int* indeg, int np){
  for (int d = blockIdx.x*blockDim.x + threadIdx.x; d < np; d += gridDim.x*blockDim.x){
    int md = mapv[d];
    if (md < 0) continue;
    int c = 0, e = rp_p[d+1];
    int j = rp_p[d];
    for (; j + 4 <= e; j += 4){
      int c0 = (mapv[col_p[j]]   >= 0);
      int c1 = (mapv[col_p[j+1]] >= 0);
      int c2 = (mapv[col_p[j+2]] >= 0);
      int c3 = (mapv[col_p[j+3]] >= 0);
      c += (c0+c1) + (c2+c3);
    }
    for (; j < e; j++) if (mapv[col_p[j]] >= 0) c++;
    indeg[md] = c;
  }
}

static __device__ void scatter_mapped_phase(const int* rp_p, const int* col_p,
    const int* mapv, const int* rp_c, int* col_c, int np){
  for (int d = blockIdx.x*blockDim.x + threadIdx.x; d < np; d += gridDim.x*blockDim.x){
    int md = mapv[d];
    if (md < 0) continue;
    int pos = rp_c[md], e = rp_p[d+1];
    int j = rp_p[d];
    for (; j + 4 <= e; j += 4){
      int m0 = mapv[col_p[j]], m1 = mapv[col_p[j+1]];
      int m2 = mapv[col_p[j+2]], m3 = mapv[col_p[j+3]];
      if (m0 >= 0) col_c[pos++] = m0;
      if (m1 >= 0) col_c[pos++] = m1;
      if (m2 >= 0) col_c[pos++] = m2;
      if (m3 >= 0) col_c[pos++] = m3;
    }
    for (; j < e; j++){
      int ms = mapv[col_p[j]];
      if (ms >= 0) col_c[pos++] = ms;
    }
  }
}

// ======================= cooperative fused kernels =======================

__global__ __launch_bounds__(256, 4) void k_edges_coop(
    const int* dst0, const int* src0,
    int* ek1, int* ev1, int* ek2, int* ev2, int* col0,
    int* ehist, int* rp0, float* dinv0, float* dinv0f){
  cg::grid_group gg = cg::this_grid();
  ehist_phase(dst0, ehist, 0);                     gg.sync();
  escatter_phase(dst0, src0, ek1, ev1, ehist, 0);  gg.sync();
  ehist_phase(ek1, ehist, 6);                      gg.sync();
  escatter_phase(ek1, ev1, ek2, ev2, ehist, 6);    gg.sync();
  ehist_phase(ek2, ehist, 12);                     gg.sync();
  escatter_phase(ek2, ev2, ek1, col0, ehist, 12);  gg.sync();
  rp_search_phase(ek1, rp0, dinv0, dinv0f, NN0);
}

__global__ __launch_bounds__(256, 4) void k_pool_csr_coop(
    const float* part, float* stats,
    float* x, const float* gamma, const float* beta, const float* pw,
    float* score, unsigned* keyA, int* idxA, unsigned* keyB, int* idxB,
    int* hist, int* perm, int* mapv, float* xk,
    const int* rp_p, const int* col_p, int* indeg, int* bsumv,
    int* rp_c, int* col_c, float* dinv_c,
    int n, int k){
  cg::grid_group gg = cg::this_grid();
  stats_phase(part, stats);                                     gg.sync();
  int nblk = (n + 1023) >> 10, P = nblk*1024;
  bnrelu_score_phase(x, stats, gamma, beta, pw, score, keyA, idxA, n, P);  gg.sync();
  radix_hist_phase(keyA, hist, 0, nblk);                        gg.sync();
  radix_scatter_phase(keyA, idxA, keyB, idxB, hist, 0, nblk);   gg.sync();
  radix_hist_phase(keyB, hist, 8, nblk);                        gg.sync();
  radix_scatter_phase(keyB, idxB, keyA, idxA, hist, 8, nblk);   gg.sync();
  radix_hist_phase(keyA, hist, 16, nblk);                       gg.sync();
  radix_scatter_phase(keyA, idxA, keyB, idxB, hist, 16, nblk);  gg.sync();
  radix_hist_phase(keyB, hist, 24, nblk);                       gg.sync();
  radix_scatter_phase(keyB, idxB, keyA, idxA, hist, 24, nblk);  gg.sync();
  select_gather_phase(idxA, x, score, perm, mapv, xk, n, k);    gg.sync();
  hist_mapped_phase(rp_p, col_p, mapv, indeg, n);               gg.sync();
  scan_part_phase(indeg, bsumv, k);                             gg.sync();
  scan_fin_rp_phase(indeg, bsumv, rp_c, dinv_c, k);             gg.sync();
  scatter_mapped_phase(rp_p, col_p, mapv, rp_c, col_c, n);
}

__global__ __launch_bounds__(256, 4) void k_bnrelu_scatter_coop(
    const float* x, const float* part, float* stats,
    const float* gamma, const float* beta,
    const int* perm, float* res, int n){
  cg::grid_group gg = cg::this_grid();
  stats_phase(part, stats);
  gg.sync();
  int total = n*64;
  float inv_n = 1.0f/(float)n;
  for (int t = blockIdx.x*blockDim.x + threadIdx.x; t < total; t += gridDim.x*blockDim.x){
    int r = t >> 6, f = t & 63;
    float mu = stats[f]*inv_n;
    float var = stats[64+f]*inv_n - mu*mu;
    float v = gamma[f]*(x[t]-mu)*(1.0f/sqrtf(var+1e-5f)) + beta[f];
    res[perm[r]*64+f] += fmaxf(v, 0.f);
  }
}

__global__ __launch_bounds__(256, 4) void k_final_coop(
    const float* x, const float* W, float* h1,
    const int* rp, const int* col, const float* dinv,
    float* out, int n){
  cg::grid_group gg = cg::this_grid();
  {
    int lane = threadIdx.x & 63, w = threadIdx.x >> 6;
    int wid = blockIdx.x*4 + w, nw = gridDim.x*4;
    float wv = W[lane];
    for (int i = wid; i < n; i += nw){
      float v = x[i*64+lane]*wv;
      for (int o = 32; o > 0; o >>= 1) v += __shfl_xor(v, o);
      if (lane == 0) h1[i] = v;
    }
  }
  gg.sync();
  for (int i = blockIdx.x*blockDim.x + threadIdx.x; i < n; i += gridDim.x*blockDim.x){
    int beg = rp[i], end = rp[i+1];
    float di = dinv[i];
    float acc = 0.f;
    int j = beg;
    for (; j + 4 <= end; j += 4){
      int s0 = col[j], s1 = col[j+1], s2 = col[j+2], s3 = col[j+3];
      float v0 = dinv[s0]*h1[s0];
      float v1 = dinv[s1]*h1[s1];
      float v2 = dinv[s2]*h1[s2];
      float v3 = dinv[s3]*h1[s3];
      acc += (v0+v1) + (v2+v3);
    }
    for (; j < end; j++) acc += dinv[col[j]]*h1[col[j]];
    float v = di*acc + di*di*h1[i];
    out[i] = 1.f/(1.f+expf(-v));
  }
}

// ======================= host =======================

extern "C" void kernel_launch(void* const* d_in, const int* in_sizes, int n_in,
                              void* d_out, int out_size, void* d_ws, size_t ws_size,
                              hipStream_t stream) {
  const float* x_in = (const float*)d_in[0];
  const int* ei = (const int*)d_in[1];
  const int* src0 = ei;
  const int* dst0 = ei + NE;
  const float* W_d[4] = {(const float*)d_in[2],(const float*)d_in[5],(const float*)d_in[8],(const float*)d_in[11]};
  const float* g_d[4] = {(const float*)d_in[3],(const float*)d_in[6],(const float*)d_in[9],(const float*)d_in[12]};
  const float* b_d[4] = {(const float*)d_in[4],(const float*)d_in[7],(const float*)d_in[10],(const float*)d_in[13]};
  const float* pw[3]  = {(const float*)d_in[14],(const float*)d_in[15],(const float*)d_in[16]};
  const float* W_u[2] = {(const float*)d_in[17],(const float*)d_in[20]};
  const float* g_u[2] = {(const float*)d_in[18],(const float*)d_in[21]};
  const float* b_u[2] = {(const float*)d_in[19],(const float*)d_in[22]};
  const float* W_out  = (const float*)d_in[23];
  float* out = (float*)d_out;

  float* base = (float*)d_ws;
  size_t off = 0;
  auto alloc = [&](size_t nf){ float* p = base + off; off += nf; return p; };
  float* x0 = alloc(5120000);
  float* x1 = alloc(2560000);
  float* x2 = alloc(1280000);
  float* x3 = alloc(640000);
  float* A  = alloc(2560000);
  int* col0 = (int*)alloc(NE);
  int* col1 = (int*)alloc(NE);
  int* col2 = (int*)alloc(NE);
  int* col3 = (int*)alloc(NE);
  int* ek1 = (int*)alloc(NE);
  int* ev1 = (int*)alloc(NE);
  int* ek2 = (int*)alloc(NE);
  int* ev2 = (int*)alloc(NE);
  int* rp0 = (int*)alloc(80001);
  int* rp1 = (int*)alloc(40001);
  int* rp2 = (int*)alloc(20001);
  int* rp3 = (int*)alloc(10001);
  int* indeg  = (int*)alloc(NN0);
  float* dinv0  = alloc(NN0);
  float* dinv0f = alloc(NN0);
  float* dinv1  = alloc(40000);
  float* dinv2  = alloc(20000);
  float* dinv3  = alloc(10000);
  float* score = alloc(NN0);
  int* mapv = (int*)alloc(NN0);
  int* p0 = (int*)alloc(40000);
  int* p1 = (int*)alloc(20000);
  int* p2 = (int*)alloc(10000);
  float* stats = alloc(128);
  float* part  = alloc(MMB_GRID*128);
  unsigned* keyA = (unsigned*)alloc(81920);
  unsigned* keyB = (unsigned*)alloc(81920);
  int* idxA = (int*)alloc(81920);
  int* idxB = (int*)alloc(81920);
  int* hist = (int*)alloc(81920);
  int* ehist = (int*)alloc(64*ENB);
  int* bsum = (int*)alloc(256);
  (void)ws_size; (void)in_sizes; (void)n_in; (void)out_size;

  const int B = 256;

  auto coopG = [&](const void* f, int want)->int{
    int per = 0;
    if (hipOccupancyMaxActiveBlocksPerMultiprocessor(&per, f, 256, 0) != hipSuccess || per < 1)
      per = 2;  // conservative fallback (launch_bounds guarantees >= 4)
    long mx = (long)per * 256;   // 256 CUs on MI355X
    return (int)(want < mx ? want : mx);
  };

  // ---- level-0 CSR: fused 3-pass edge radix sort + rp/dinv ----
  {
    static int G = 0; if (!G) G = coopG((const void*)k_edges_coop, 625);
    void* a[] = {(void*)&dst0,(void*)&src0,(void*)&ek1,(void*)&ev1,(void*)&ek2,(void*)&ev2,
                 (void*)&col0,(void*)&ehist,(void*)&rp0,(void*)&dinv0,(void*)&dinv0f};
    hipLaunchCooperativeKernel((const void*)k_edges_coop, dim3(G), dim3(256), a, 0, stream);
  }

  auto conv = [&](const float* xin, const float* W, int n,
                  const int* rp, const int* col, const float* dv, float* dstb){
    k_conv64<<<MMB_GRID, B, 0, stream>>>(rp, col, dv, xin, W, dstb, part, n);
  };

  auto pool_csr = [&](float* xb, const float* gm, const float* bt, const float* pwv,
                      const int* rpp, const int* colp, int* pm,
                      int* rpc, int* colc, float* dvc, int n2, int k2){
    static int G = 0; if (!G) G = coopG((const void*)k_pool_csr_coop, 512);
    void* a[] = {(void*)&part,(void*)&stats,(void*)&xb,(void*)&gm,(void*)&bt,(void*)&pwv,
                 (void*)&score,(void*)&keyA,(void*)&idxA,(void*)&keyB,(void*)&idxB,(void*)&hist,
                 (void*)&pm,(void*)&mapv,(void*)&A,
                 (void*)&rpp,(void*)&colp,(void*)&indeg,(void*)&bsum,
                 (void*)&rpc,(void*)&colc,(void*)&dvc,
                 (void*)&n2,(void*)&k2};
    hipLaunchCooperativeKernel((const void*)k_pool_csr_coop, dim3(G), dim3(256), a, 0, stream);
  };

  auto bnrelu_up = [&](const float* xb, const float* gm, const float* bt,
                       const int* pm, float* res, int n2){
    static int G = 0; if (!G) G = coopG((const void*)k_bnrelu_scatter_coop, 512);
    void* a[] = {(void*)&xb,(void*)&part,(void*)&stats,(void*)&gm,(void*)&bt,
                 (void*)&pm,(void*)&res,(void*)&n2};
    hipLaunchCooperativeKernel((const void*)k_bnrelu_scatter_coop, dim3(G), dim3(256), a, 0, stream);
  };

  // ---- down path ----
  k_conv3<<<MMB_GRID, B, 0, stream>>>(rp0, col0, dinv0, x_in, W_d[0], x0, part, NN0);
  pool_csr(x0, g_d[0], b_d[0], pw[0], rp0, col0, p0, rp1, col1, dinv1, NN0, 40000);

  conv(A, W_d[1], 40000, rp1, col1, dinv1, x1);
  pool_csr(x1, g_d[1], b_d[1], pw[1], rp1, col1, p1, rp2, col2, dinv2, 40000, 20000);

  conv(A, W_d[2], 20000, rp2, col2, dinv2, x2);
  pool_csr(x2, g_d[2], b_d[2], pw[2], rp2, col2, p2, rp3, col3, dinv3, 20000, 10000);

  conv(A, W_d[3], 10000, rp3, col3, dinv3, x3);

  // ---- up path (stats-reduce fused into BN+ReLU+scatter-add) ----
  bnrelu_up(x3, g_d[3], b_d[3], p2, x2, 10000);
  conv(x2, W_u[0], 20000, rp2, col2, dinv2, A);
  bnrelu_up(A, g_u[0], b_u[0], p1, x1, 20000);
  conv(x1, W_u[1], 40000, rp1, col1, dinv1, A);
  bnrelu_up(A, g_u[1], b_u[1], p0, x0, 40000);

  // ---- final conv (fill = 1.0) fused with sigmoid ----
  {
    static int G = 0; if (!G) G = coopG((const void*)k_final_coop, 512);
    float* h1 = score;  // reuse
    int n2 = NN0;
    void* a[] = {(void*)&x0,(void*)&W_out,(void*)&h1,(void*)&rp0,(void*)&col0,
                 (void*)&dinv0f,(void*)&out,(void*)&n2};
    hipLaunchCooperativeKernel((const void*)k_final_coop, dim3(G), dim3(256), a, 0, stream);
  }
}